// Round 6
// baseline (567.270 us; speedup 1.0000x reference)
//
#include <hip/hip_runtime.h>

typedef __attribute__((ext_vector_type(8)))  short short8;
typedef __attribute__((ext_vector_type(4)))  float f32x4;
typedef __attribute__((ext_vector_type(16))) float f32x16;

#define L2E 1.44269504088896340736f

__device__ __forceinline__ unsigned short f2bf(float x) {
    union { float f; unsigned int u; } v; v.f = x;
    unsigned int u = v.u;
    unsigned int r = (u + 0x7FFFu + ((u >> 16) & 1u)) >> 16;
    return (unsigned short)r;
}

__device__ __forceinline__ float mishf(float x) {
    float u = __builtin_amdgcn_exp2f(x * L2E);
    float t = u * (u + 2.0f);
    return x * t * __builtin_amdgcn_rcpf(t + 2.0f);
}

// p = adj * exp(mish(s1+s2)); log2-domain inputs (pre-scaled by log2 e),
// u = e^{s1}*e^{s2} from precomputed factors; adj is exactly 0.0/1.0 -> mask by mul.
__device__ __forceinline__ float pval(float aj, float svL, float ev, float s1v, float e1v) {
    float xL = s1v + svL;
    float u  = e1v * ev;
    float t  = u * (u + 2.0f);
    float m  = xL * t * __builtin_amdgcn_rcpf(t + 2.0f);
    return aj * __builtin_amdgcn_exp2f(m);
}

__device__ __forceinline__ short bfr(float p) {
    union { float f; unsigned int u; } b; b.f = p;
    return (short)((b.u + 0x8000u) >> 16);
}

// ---------------- kernel: W (512x256 f32) -> WT bf16 (256x512) ----------------
__global__ void k_cvt_wt(const float* __restrict__ W, unsigned short* __restrict__ wt) {
    int c = blockIdx.x;
    int t = threadIdx.x;
    wt[c * 512 + t]       = f2bf(W[(size_t)t * 256 + c]);
    wt[c * 512 + t + 256] = f2bf(W[(size_t)(t + 256) * 256 + c]);
}

// ------- h = input @ W (bf16 MFMA) fused with s1/s2/e2 epilogue ---------------
__global__ __launch_bounds__(256) void k_gemm_h(const float* __restrict__ input,
                                                const unsigned short* __restrict__ wt,
                                                const float* __restrict__ a,
                                                unsigned short* __restrict__ hbt,
                                                float* __restrict__ s1L,
                                                float* __restrict__ s2L,
                                                float* __restrict__ e2g) {
    __shared__ float red[2][4][16];
    int tid = threadIdx.x;
    int w = tid >> 6, lane = tid & 63, g = lane >> 4, r = lane & 15;
    int base = blockIdx.x * 16;

    f32x4 acc[4];
#pragma unroll
    for (int n = 0; n < 4; ++n) acc[n] = (f32x4)0.0f;

    const float* arow = input + (size_t)(base + r) * 512 + g * 8;
    const unsigned short* wp = wt + (size_t)(w * 64 + r) * 512 + g * 8;
#pragma unroll 4
    for (int kb = 0; kb < 512; kb += 32) {
        float4 a0 = *(const float4*)(arow + kb);
        float4 a1 = *(const float4*)(arow + kb + 4);
        short8 af;
        af[0] = (short)f2bf(a0.x); af[1] = (short)f2bf(a0.y);
        af[2] = (short)f2bf(a0.z); af[3] = (short)f2bf(a0.w);
        af[4] = (short)f2bf(a1.x); af[5] = (short)f2bf(a1.y);
        af[6] = (short)f2bf(a1.z); af[7] = (short)f2bf(a1.w);
#pragma unroll
        for (int n2 = 0; n2 < 4; ++n2) {
            short8 bf = *(const short8*)(wp + n2 * 8192 + kb);
            acc[n2] = __builtin_amdgcn_mfma_f32_16x16x32_bf16(af, bf, acc[n2], 0, 0, 0);
        }
    }
    int rowc = base + g * 4;
#pragma unroll
    for (int n2 = 0; n2 < 4; ++n2) {
        int col = w * 64 + n2 * 16 + r;
        ushort4 pk;
        pk.x = f2bf(acc[n2][0]); pk.y = f2bf(acc[n2][1]);
        pk.z = f2bf(acc[n2][2]); pk.w = f2bf(acc[n2][3]);
        *(ushort4*)(hbt + (size_t)col * 8192 + rowc) = pk;
    }
    float p1[4] = {0,0,0,0}, p2[4] = {0,0,0,0};
#pragma unroll
    for (int n2 = 0; n2 < 4; ++n2) {
        float a1v = a[w * 64 + n2 * 16 + r];
        float a2v = a[256 + w * 64 + n2 * 16 + r];
#pragma unroll
        for (int i = 0; i < 4; ++i) {
            p1[i] += acc[n2][i] * a1v;
            p2[i] += acc[n2][i] * a2v;
        }
    }
#pragma unroll
    for (int off = 8; off >= 1; off >>= 1) {
#pragma unroll
        for (int i = 0; i < 4; ++i) {
            p1[i] += __shfl_xor(p1[i], off);
            p2[i] += __shfl_xor(p2[i], off);
        }
    }
    if (r == 0) {
#pragma unroll
        for (int i = 0; i < 4; ++i) {
            red[0][w][g * 4 + i] = p1[i];
            red[1][w][g * 4 + i] = p2[i];
        }
    }
    __syncthreads();
    if (tid < 16) {
        float s1 = red[0][0][tid] + red[0][1][tid] + red[0][2][tid] + red[0][3][tid];
        float s2 = red[1][0][tid] + red[1][1][tid] + red[1][2][tid] + red[1][3][tid];
        s1L[base + tid] = s1 * L2E;
        float s2l = s2 * L2E;
        s2L[base + tid] = s2l;
        e2g[base + tid] = __builtin_amdgcn_exp2f(s2l);
    }
}

// ---------------- fused masked-softmax PV: barrier-free main loop -------------
// 256 blocks x 512 thr (8 waves). Block owns 32 rows; wave w owns k in
// [w*1024,(w+1)*1024). adj streamed from HBM (nt, 4-deep prefetch), hbt/s2/e2
// from L1/L2. MFMA 32x32x16, acc 8x f32x16 (all 256 feats). LDS tree-reduce
// + divide + mish at the end (2 barriers total).
#define NT(p) __builtin_nontemporal_load((const f32x4*)(p))
__global__ __launch_bounds__(512, 2) void k_fused(const float* __restrict__ adj,
                                                  const unsigned short* __restrict__ hbt,
                                                  const float* __restrict__ s1L,
                                                  const float* __restrict__ s2Lg,
                                                  const float* __restrict__ e2g,
                                                  float* __restrict__ out) {
    __shared__ float red[4][32][257];   // 4 partial tiles (rows x feats)
    __shared__ float zred[8][32];

    int tid = threadIdx.x;
    int w = tid >> 6, lane = tid & 63;
    int lo5 = lane & 31, hi = lane >> 5;
    int brow = blockIdx.x * 32;
    int rowM = brow + lo5;
    int k0 = w * 1024;

    float s1v = s1L[rowM];
    float e1v = __builtin_amdgcn_exp2f(s1v);

    const float* ap  = adj + (size_t)rowM * 8192 + k0 + hi * 8;
    const float* svp = s2Lg + k0 + hi * 8;
    const float* evp = e2g  + k0 + hi * 8;
    const char*  bb  = (const char*)hbt + (size_t)lo5 * 16384 + (size_t)k0 * 2 + hi * 16;

    f32x16 acc[8];
#pragma unroll
    for (int n = 0; n < 8; ++n) acc[n] = (f32x16)0.0f;
    float zacc = 0.0f;

#define STEP(s, A0, A1) do {                                                   \
        f32x4 sv0 = *(const f32x4*)(svp + (s) * 16);                           \
        f32x4 sv1 = *(const f32x4*)(svp + (s) * 16 + 4);                       \
        f32x4 ev0 = *(const f32x4*)(evp + (s) * 16);                           \
        f32x4 ev1 = *(const f32x4*)(evp + (s) * 16 + 4);                       \
        float p0 = pval(A0[0], sv0[0], ev0[0], s1v, e1v);                      \
        float p1 = pval(A0[1], sv0[1], ev0[1], s1v, e1v);                      \
        float p2 = pval(A0[2], sv0[2], ev0[2], s1v, e1v);                      \
        float p3 = pval(A0[3], sv0[3], ev0[3], s1v, e1v);                      \
        float p4 = pval(A1[0], sv1[0], ev1[0], s1v, e1v);                      \
        float p5 = pval(A1[1], sv1[1], ev1[1], s1v, e1v);                      \
        float p6 = pval(A1[2], sv1[2], ev1[2], s1v, e1v);                      \
        float p7 = pval(A1[3], sv1[3], ev1[3], s1v, e1v);                      \
        zacc += ((p0 + p1) + (p2 + p3)) + ((p4 + p5) + (p6 + p7));             \
        short8 af;                                                             \
        af[0] = bfr(p0); af[1] = bfr(p1); af[2] = bfr(p2); af[3] = bfr(p3);    \
        af[4] = bfr(p4); af[5] = bfr(p5); af[6] = bfr(p6); af[7] = bfr(p7);    \
        const char* bs_ = bb + (s) * 32;                                       \
        _Pragma("unroll")                                                      \
        for (int n_ = 0; n_ < 8; ++n_) {                                       \
            short8 bf_ = *(const short8*)(bs_ + (size_t)n_ * 524288);          \
            acc[n_] = __builtin_amdgcn_mfma_f32_32x32x16_bf16(af, bf_, acc[n_], 0, 0, 0); \
        }                                                                      \
    } while (0)

    // 4-deep adj prefetch (steps 0..3)
    f32x4 aA0 = NT(ap);            f32x4 aA1 = NT(ap + 4);
    f32x4 aB0 = NT(ap + 16);       f32x4 aB1 = NT(ap + 20);
    f32x4 aC0 = NT(ap + 32);       f32x4 aC1 = NT(ap + 36);
    f32x4 aD0 = NT(ap + 48);       f32x4 aD1 = NT(ap + 52);

    for (int s = 0; s < 64; s += 4) {
        STEP(s, aA0, aA1);
        { int t = (s + 4 < 64) ? s + 4 : 60; aA0 = NT(ap + t * 16); aA1 = NT(ap + t * 16 + 4); }
        STEP(s + 1, aB0, aB1);
        { int t = (s + 5 < 64) ? s + 5 : 61; aB0 = NT(ap + t * 16); aB1 = NT(ap + t * 16 + 4); }
        STEP(s + 2, aC0, aC1);
        { int t = (s + 6 < 64) ? s + 6 : 62; aC0 = NT(ap + t * 16); aC1 = NT(ap + t * 16 + 4); }
        STEP(s + 3, aD0, aD1);
        { int t = (s + 7 < 64) ? s + 7 : 63; aD0 = NT(ap + t * 16); aD1 = NT(ap + t * 16 + 4); }
    }
#undef STEP

    // Z: combine the two hi-halves of each row's k-slice
    float ztot = zacc + __shfl_xor(zacc, 32);

    // phase 1: waves 0-3 deposit partial tiles; everyone writes Z partials
    if (w < 4) {
#pragma unroll
        for (int n = 0; n < 8; ++n)
#pragma unroll
            for (int e = 0; e < 16; ++e) {
                int rr = (e & 3) + ((e >> 2) << 3) + hi * 4;
                red[w][rr][n * 32 + lo5] = acc[n][e];
            }
    }
    if (hi == 0) zred[w][lo5] = ztot;
    __syncthreads();
    // phase 2: waves 4-7 accumulate into tiles 0-3
    if (w >= 4) {
#pragma unroll
        for (int n = 0; n < 8; ++n)
#pragma unroll
            for (int e = 0; e < 16; ++e) {
                int rr = (e & 3) + ((e >> 2) << 3) + hi * 4;
                red[w - 4][rr][n * 32 + lo5] += acc[n][e];
            }
    }
    __syncthreads();
    // phase 3: final 4-way sum, divide by Z, mish, store
    {
        int r0 = tid >> 4, fb = (tid & 15) * 16;
        float z = 0.0f;
#pragma unroll
        for (int q = 0; q < 8; ++q) z += zred[q][r0];
        float rz = __builtin_amdgcn_rcpf(z);
        float* op = out + (size_t)(brow + r0) * 256 + fb;
#pragma unroll
        for (int ff = 0; ff < 16; ++ff) {
            float s4 = red[0][r0][fb + ff] + red[1][r0][fb + ff]
                     + red[2][r0][fb + ff] + red[3][r0][fb + ff];
            op[ff] = mishf(s4 * rz);
        }
    }
}

extern "C" void kernel_launch(void* const* d_in, const int* in_sizes, int n_in,
                              void* d_out, int out_size, void* d_ws, size_t ws_size,
                              hipStream_t stream) {
    const float* input = (const float*)d_in[0];
    const float* adj   = (const float*)d_in[1];
    const float* W     = (const float*)d_in[2];
    const float* a     = (const float*)d_in[3];
    float* out = (float*)d_out;

    char* ws = (char*)d_ws;
    unsigned short* wt  = (unsigned short*)ws;                 // 256 KB
    unsigned short* hbt = (unsigned short*)(ws + 262144);      // 4 MB (feat-major 256x8192)
    float* s1L          = (float*)(ws + 4456448);              // 32 KB
    float* s2L          = (float*)(ws + 4489216);              // 32 KB
    float* e2g          = (float*)(ws + 4521984);              // 32 KB

    hipLaunchKernelGGL(k_cvt_wt, dim3(256), dim3(256), 0, stream, W, wt);
    hipLaunchKernelGGL(k_gemm_h, dim3(512), dim3(256), 0, stream, input, wt, a, hbt, s1L, s2L, e2g);
    hipLaunchKernelGGL(k_fused, dim3(256), dim3(512), 0, stream, adj, hbt, s1L, s2L, e2g, out);
}

// Round 7
// 478.154 us; speedup vs baseline: 1.1864x; 1.1864x over previous
//
#include <hip/hip_runtime.h>

typedef __attribute__((ext_vector_type(8)))  short short8;
typedef __attribute__((ext_vector_type(4)))  float f32x4;
typedef __attribute__((ext_vector_type(16))) float f32x16;

#define L2E 1.44269504088896340736f

__device__ __forceinline__ unsigned short f2bf(float x) {
    union { float f; unsigned int u; } v; v.f = x;
    unsigned int u = v.u;
    unsigned int r = (u + 0x7FFFu + ((u >> 16) & 1u)) >> 16;
    return (unsigned short)r;
}

__device__ __forceinline__ float mishf(float x) {
    float u = __builtin_amdgcn_exp2f(x * L2E);
    float t = u * (u + 2.0f);
    return x * t * __builtin_amdgcn_rcpf(t + 2.0f);
}

__device__ __forceinline__ short bfr(float p) {
    union { float f; unsigned int u; } b; b.f = p;
    return (short)((b.u + 0x8000u) >> 16);
}

typedef __attribute__((address_space(1))) const unsigned int guint;
typedef __attribute__((address_space(3))) unsigned int luint;
__device__ __forceinline__ void lds16(const void* g, void* l) {
    __builtin_amdgcn_global_load_lds((guint*)g, (luint*)l, 16, 0, 0);
}

// ---------------- adj (0/1 f32, 256 MB) -> bitmask (8 MB), streaming ----------
__global__ __launch_bounds__(256) void k_pack(const float* __restrict__ adj,
                                              unsigned int* __restrict__ mask) {
    int wid = blockIdx.x * 4 + (threadIdx.x >> 6);   // one wave per row
    int lane = threadIdx.x & 63;
    const float* row = adj + (size_t)wid * 8192 + lane;
    unsigned int* mrow = mask + wid * 256;
#pragma unroll 2
    for (int base = 0; base < 8192; base += 256) {
        float v0 = row[base];
        float v1 = row[base + 64];
        float v2 = row[base + 128];
        float v3 = row[base + 192];
        unsigned long long b0 = __ballot(v0 > 0.5f);
        unsigned long long b1 = __ballot(v1 > 0.5f);
        unsigned long long b2 = __ballot(v2 > 0.5f);
        unsigned long long b3 = __ballot(v3 > 0.5f);
        if (lane == 0) {
            *(ulonglong2*)(mrow + (base >> 5))     = make_ulonglong2(b0, b1);
            *(ulonglong2*)(mrow + (base >> 5) + 4) = make_ulonglong2(b2, b3);
        }
    }
}

// ---------------- kernel: W (512x256 f32) -> WT bf16 (256x512) ----------------
__global__ void k_cvt_wt(const float* __restrict__ W, unsigned short* __restrict__ wt) {
    int c = blockIdx.x;
    int t = threadIdx.x;
    wt[c * 512 + t]       = f2bf(W[(size_t)t * 256 + c]);
    wt[c * 512 + t + 256] = f2bf(W[(size_t)(t + 256) * 256 + c]);
}

// ------- h = input @ W (bf16 MFMA) fused with s1/s2 epilogue ------------------
__global__ __launch_bounds__(256) void k_gemm_h(const float* __restrict__ input,
                                                const unsigned short* __restrict__ wt,
                                                const float* __restrict__ a,
                                                unsigned short* __restrict__ hbt,
                                                float* __restrict__ s1L,
                                                float* __restrict__ s2L) {
    __shared__ float red[2][4][16];
    int tid = threadIdx.x;
    int w = tid >> 6, lane = tid & 63, g = lane >> 4, r = lane & 15;
    int base = blockIdx.x * 16;

    f32x4 acc[4];
#pragma unroll
    for (int n = 0; n < 4; ++n) acc[n] = (f32x4)0.0f;

    const float* arow = input + (size_t)(base + r) * 512 + g * 8;
    const unsigned short* wp = wt + (size_t)(w * 64 + r) * 512 + g * 8;
#pragma unroll 4
    for (int kb = 0; kb < 512; kb += 32) {
        float4 a0 = *(const float4*)(arow + kb);
        float4 a1 = *(const float4*)(arow + kb + 4);
        short8 af;
        af[0] = (short)f2bf(a0.x); af[1] = (short)f2bf(a0.y);
        af[2] = (short)f2bf(a0.z); af[3] = (short)f2bf(a0.w);
        af[4] = (short)f2bf(a1.x); af[5] = (short)f2bf(a1.y);
        af[6] = (short)f2bf(a1.z); af[7] = (short)f2bf(a1.w);
#pragma unroll
        for (int n2 = 0; n2 < 4; ++n2) {
            short8 bf = *(const short8*)(wp + n2 * 8192 + kb);
            acc[n2] = __builtin_amdgcn_mfma_f32_16x16x32_bf16(af, bf, acc[n2], 0, 0, 0);
        }
    }
    int rowc = base + g * 4;
#pragma unroll
    for (int n2 = 0; n2 < 4; ++n2) {
        int col = w * 64 + n2 * 16 + r;
        ushort4 pk;
        pk.x = f2bf(acc[n2][0]); pk.y = f2bf(acc[n2][1]);
        pk.z = f2bf(acc[n2][2]); pk.w = f2bf(acc[n2][3]);
        *(ushort4*)(hbt + (size_t)col * 8192 + rowc) = pk;
    }
    float p1[4] = {0,0,0,0}, p2[4] = {0,0,0,0};
#pragma unroll
    for (int n2 = 0; n2 < 4; ++n2) {
        float a1v = a[w * 64 + n2 * 16 + r];
        float a2v = a[256 + w * 64 + n2 * 16 + r];
#pragma unroll
        for (int i = 0; i < 4; ++i) {
            p1[i] += acc[n2][i] * a1v;
            p2[i] += acc[n2][i] * a2v;
        }
    }
#pragma unroll
    for (int off = 8; off >= 1; off >>= 1) {
#pragma unroll
        for (int i = 0; i < 4; ++i) {
            p1[i] += __shfl_xor(p1[i], off);
            p2[i] += __shfl_xor(p2[i], off);
        }
    }
    if (r == 0) {
#pragma unroll
        for (int i = 0; i < 4; ++i) {
            red[0][w][g * 4 + i] = p1[i];
            red[1][w][g * 4 + i] = p2[i];
        }
    }
    __syncthreads();
    if (tid < 16) {
        float s1 = red[0][0][tid] + red[0][1][tid] + red[0][2][tid] + red[0][3][tid];
        float s2 = red[1][0][tid] + red[1][1][tid] + red[1][2][tid] + red[1][3][tid];
        s1L[base + tid] = s1 * L2E;
        s2L[base + tid] = s2 * L2E;
    }
}

// ---------------- PV: LDS-staged, 1-barrier/step, counted vmcnt ---------------
// grid (64 row-blocks, 8 k-chunks) = 512 blocks = 2/CU. 256 thr = 4 waves x
// 32 rows (BM=128). MFMA 32x32x16. Step = 32 k; 4 LDS bufs, depth-2 staging.
__global__ __launch_bounds__(256, 2) void k_pv(const unsigned int* __restrict__ mask,
                                               const unsigned short* __restrict__ hbt,
                                               const float* __restrict__ s1Lg,
                                               const float* __restrict__ s2Lg,
                                               float* __restrict__ pS,
                                               float* __restrict__ pZ) {
    __shared__ __align__(16) unsigned short buf[4][8192]; // 4 x (256 feat x 32 k)
    __shared__ __align__(16) float s2s[1024];             // chunk's s2L slice

    int tid = threadIdx.x;
    int w = tid >> 6, lane = tid & 63;
    int lo5 = lane & 31, hi = lane >> 5;
    int mb = blockIdx.x, chunk = blockIdx.y;
    int kc = chunk * 1024;
    int rowbase = mb * 128 + w * 32;
    float s1v = s1Lg[rowbase + lo5];
    const unsigned int* mkp = mask + (size_t)(rowbase + lo5) * 256 + chunk * 32;

    // staging: thread t, round j: feat = j*64 + (t>>2); LDS chunk slot (t&3)
    // holds global 16B-chunk (t&3) ^ ((feat>>1)&3)  [involution, rule 21]
    int feat0 = tid >> 2;
    const unsigned short* hsrc = hbt + (size_t)feat0 * 8192 + kc
                                     + (((tid & 3) ^ ((feat0 >> 1) & 3)) << 3);
    int rdswz = (lo5 >> 1) & 3;

    f32x16 acc[8];
#pragma unroll
    for (int n = 0; n < 8; ++n) acc[n] = (f32x16)0.0f;
    f32x16 accz = (f32x16)0.0f;

    short8 onef;
    {
        short ov = (lo5 == 0) ? (short)0x3F80 : (short)0;
#pragma unroll
        for (int j = 0; j < 8; ++j) onef[j] = ov;
    }

    unsigned int mk0, mk1, mk2, mk3;

#define STAGE(ss, p) do {                                                      \
        int ko_ = (((ss) < 32) ? (ss) : 31) * 32;                              \
        char* lb_ = (char*)&buf[0][0] + (p) * 16384 + tid * 16;                \
        _Pragma("unroll")                                                      \
        for (int j_ = 0; j_ < 4; ++j_)                                         \
            lds16(hsrc + (size_t)j_ * 524288 + ko_, lb_ + j_ * 4096);          \
    } while (0)

#define BAR() do {                                                             \
        __builtin_amdgcn_sched_barrier(0);                                     \
        __builtin_amdgcn_s_barrier();                                          \
        __builtin_amdgcn_sched_barrier(0);                                     \
    } while (0)

#define VW() do {                                                              \
        asm volatile("s_waitcnt vmcnt(10)" ::: "memory");                      \
        __builtin_amdgcn_sched_barrier(0);                                     \
    } while (0)

#define COMP(p, MK, ss) do {                                                   \
        const char* tb_ = (const char*)&buf[0][0] + (p) * 16384 + lo5 * 64;    \
        _Pragma("unroll")                                                      \
        for (int ksub = 0; ksub < 2; ++ksub) {                                 \
            int svb_ = (ss) * 128 + ksub * 64 + hi * 32;                       \
            f32x4 sv0 = *(const f32x4*)((const char*)s2s + svb_);              \
            f32x4 sv1 = *(const f32x4*)((const char*)s2s + svb_ + 16);         \
            int sh_ = ksub * 16 + hi * 8;                                      \
            short8 af;                                                         \
            _Pragma("unroll")                                                  \
            for (int j_ = 0; j_ < 8; ++j_) {                                   \
                float svL = (j_ < 4) ? sv0[j_ & 3] : sv1[j_ & 3];              \
                float xL = s1v + svL;                                          \
                float u = __builtin_amdgcn_exp2f(xL);                          \
                float t = u * (u + 2.0f);                                      \
                float m = xL * t * __builtin_amdgcn_rcpf(t + 2.0f);            \
                float pv = __builtin_amdgcn_exp2f(m);                          \
                pv = ((MK >> (sh_ + j_)) & 1u) ? pv : 0.0f;                    \
                af[j_] = bfr(pv);                                              \
            }                                                                  \
            const char* tbl_ = tb_ + ((((ksub * 2 + hi) ^ rdswz)) << 4);       \
            _Pragma("unroll")                                                  \
            for (int n_ = 0; n_ < 8; ++n_) {                                   \
                short8 bf_ = *(const short8*)(tbl_ + n_ * 2048);               \
                acc[n_] = __builtin_amdgcn_mfma_f32_32x32x16_bf16(af, bf_, acc[n_], 0, 0, 0); \
            }                                                                  \
            accz = __builtin_amdgcn_mfma_f32_32x32x16_bf16(af, onef, accz, 0, 0, 0);          \
        }                                                                      \
    } while (0)

    // prologue: s2 slice + two tiles in flight, then drain own s2s and barrier
    lds16(s2Lg + kc + tid * 4, (char*)s2s + tid * 16);
    STAGE(0, 0); mk0 = mkp[0];
    STAGE(1, 1); mk1 = mkp[1];
    asm volatile("s_waitcnt vmcnt(10)" ::: "memory");
    __builtin_amdgcn_sched_barrier(0);
    __builtin_amdgcn_s_barrier();

    for (int s = 0; s < 32; s += 4) {
        BAR(); STAGE(s + 2, 2); mk2 = mkp[(s + 2 < 32) ? s + 2 : 31];
        VW();  COMP(0, mk0, s);
        BAR(); STAGE(s + 3, 3); mk3 = mkp[(s + 3 < 32) ? s + 3 : 31];
        VW();  COMP(1, mk1, s + 1);
        BAR(); STAGE(s + 4, 0); mk0 = mkp[(s + 4 < 32) ? s + 4 : 31];
        VW();  COMP(2, mk2, s + 2);
        BAR(); STAGE(s + 5, 1); mk1 = mkp[(s + 5 < 32) ? s + 5 : 31];
        VW();  COMP(3, mk3, s + 3);
    }

    // epilogue: partial S (C layout: col=lane&31, row=(e&3)+8*(e>>2)+4*hi)
    {
        float* ps = pS + ((size_t)chunk << 21) + (size_t)rowbase * 256;
#pragma unroll
        for (int n = 0; n < 8; ++n) {
#pragma unroll
            for (int e = 0; e < 16; ++e) {
                int rl = (e & 3) + ((e >> 2) << 3) + hi * 4;
                ps[(size_t)rl * 256 + n * 32 + lo5] = acc[n][e];
            }
        }
    }
    if (lo5 == 0) {
        float* pz = pZ + chunk * 8192 + rowbase;
#pragma unroll
        for (int e = 0; e < 16; ++e) {
            int rl = (e & 3) + ((e >> 2) << 3) + hi * 4;
            pz[rl] = accz[e];
        }
    }
#undef STAGE
#undef BAR
#undef VW
#undef COMP
}

// ---------------- final: reduce 8 partials, divide, mish ----------------------
__global__ void k_final(const float* __restrict__ pS, const float* __restrict__ pZ,
                        float* __restrict__ out) {
    int i = blockIdx.x;
    int f = threadIdx.x;
    size_t o = (size_t)i * 256 + f;
    float sv = 0.0f, z = 0.0f;
#pragma unroll
    for (int c = 0; c < 8; ++c) {
        sv += pS[o + ((size_t)c << 21)];
        z  += pZ[c * 8192 + i];
    }
    out[o] = mishf(sv / z);
}

extern "C" void kernel_launch(void* const* d_in, const int* in_sizes, int n_in,
                              void* d_out, int out_size, void* d_ws, size_t ws_size,
                              hipStream_t stream) {
    const float* input = (const float*)d_in[0];
    const float* adj   = (const float*)d_in[1];
    const float* W     = (const float*)d_in[2];
    const float* a     = (const float*)d_in[3];
    float* out = (float*)d_out;

    char* ws = (char*)d_ws;
    unsigned short* wt   = (unsigned short*)ws;                // 256 KB
    unsigned short* hbt  = (unsigned short*)(ws + 262144);     // 4 MB (feat-major)
    float* s1L           = (float*)(ws + 4456448);             // 32 KB
    float* s2L           = (float*)(ws + 4489216);             // 32 KB
    unsigned int* mask   = (unsigned int*)(ws + 4521984);      // 8 MB
    float* pS            = (float*)(ws + 12910592);            // 64 MB (8 x 8192 x 256)
    float* pZ            = (float*)(ws + 80019456);            // 256 KB (end ~80.3 MB)

    hipLaunchKernelGGL(k_pack, dim3(2048), dim3(256), 0, stream, adj, mask);
    hipLaunchKernelGGL(k_cvt_wt, dim3(256), dim3(256), 0, stream, W, wt);
    hipLaunchKernelGGL(k_gemm_h, dim3(512), dim3(256), 0, stream, input, wt, a, hbt, s1L, s2L);
    hipLaunchKernelGGL(k_pv, dim3(64, 8), dim3(256), 0, stream, mask, hbt, s1L, s2L, pS, pZ);
    hipLaunchKernelGGL(k_final, dim3(8192), dim3(256), 0, stream, pS, pZ, out);
}